// Round 7
// baseline (226.550 us; speedup 1.0000x reference)
//
#include <hip/hip_runtime.h>

// CTC batch cost (keras ctc_batch_cost semantics). B=512,T=512,C=128,L=32,S=65.
// One wave per batch element. BIDIRECTIONAL: forward alpha over rows 1..256 and
// backward beta over rows 511..257 interleaved in the same wave, meet at 256:
//   loglik = sum_s alpha_256[s] * beta_256[s].
// Fwd: lane s holds alpha[s], lane 63 extra carries alpha[64].
// Bwd: lane s holds beta[s+1], lane 0 extra carries beta[0] (exact mirror).
// Probability domain; exact pow2 per-chain rescale (R3-proven: 16 samples,
// stride 4, target 2^0). MERGE IS LOG-DOMAIN: with per-chain max normalized to
// 2^0, the joint product alpha*beta at the meeting row is generically ~2^-110
// (path-count entropy puts alpha's mass at high states, beta's at low states),
// which underflowed fp32 in R5/R6 -> p=0 -> -log(0)=inf. Logsumexp avoids it.

#define EPSF 1e-7f

constexpr int T_ = 512;
constexpr int C_ = 128;
constexpr int L_ = 32;
constexpr int NF = 17;   // fwd gathers per 4-row group
constexpr int NB = 28;   // bwd gathers per 4-row group

__launch_bounds__(64)
__global__ void ctc_loss_kernel(const int* __restrict__ y_true,
                                const float* __restrict__ y_pred,
                                float* __restrict__ out) {
    const int bidx = blockIdx.x;
    const int lane = threadIdx.x;

    const float* bb  = y_pred + (size_t)bidx * T_ * C_;
    const int*   lbl = y_true + bidx * L_;

    // ---- forward tables: state v = lane - i ----
    int   cf[7];   // byte offsets of class(lane-i)
    float sg[7];   // skip gate INTO state lane-i
    float msk[9];
#pragma unroll
    for (int i = 0; i < 7; ++i) {
        const int v = lane - i;
        int c = C_ - 1; float s = 0.f;
        if (v >= 1 && (v & 1)) {
            c = lbl[(v - 1) >> 1];
            if (v >= 3 && c != lbl[((v - 1) >> 1) - 1]) s = 1.f;
        }
        cf[i] = c * 4; sg[i] = s;
    }
#pragma unroll
    for (int i = 0; i < 9; ++i) msk[i] = (lane >= i) ? 1.f : 0.f;

    // ---- backward tables: state u = lane + 1 + i ----
    int   cb[9];   // byte offsets of class(lane+1+i)
    float gd[7];   // skip gate for transition (lane+1+i) -> (lane+3+i)
    float mdn[9];
#pragma unroll
    for (int i = 0; i < 9; ++i) {
        const int u = lane + 1 + i;
        int c = C_ - 1;
        if (u <= 64 && (u & 1)) c = lbl[(u - 1) >> 1];
        cb[i] = c * 4;
        mdn[i] = (lane + i <= 63) ? 1.f : 0.f;
    }
#pragma unroll
    for (int i = 0; i < 7; ++i) {
        const int v = lane + i + 3;
        float g = 0.f;
        if (v <= 64 && (v & 1) && lbl[(v - 1) >> 1] != lbl[((v - 1) >> 1) - 1]) g = 1.f;
        gd[i] = g;
    }

    auto gat = [](const float* r, int boff) -> float {
        return *(const float*)((const char*)r + boff);
    };

    // ---- state ----
    float a   = (lane < 2) ? (gat(bb, cf[0]) + EPSF) : 0.f;  // alpha[lane]
    float a64 = 0.f;                                          // alpha[64] (lane 63)
    float b   = (lane >= 62) ? 1.f : 0.f;                     // beta[lane+1] @ row 511
    float b0  = 0.f;                                          // beta[0] (lane 0)
    int ef = 0, eb = 0;

    // ---- prefetch buffers ----
    float Qf[3][NF];
    float Qb[3][NB];

    auto loadqf = [&](float (&Qk)[NF], const float* r) {
        Qk[0]  = gat(r, cf[0]);          Qk[1]  = gat(r, cf[1]);
        Qk[2]  = gat(r, cf[2]);          Qk[3]  = gat(r, cf[3]);
        Qk[4]  = gat(r, cf[4]);          Qk[5]  = gat(r, cf[5]);
        Qk[6]  = gat(r, cf[6]);
        Qk[7]  = gat(r + C_, cf[0]);     Qk[8]  = gat(r + C_, cf[1]);
        Qk[9]  = gat(r + C_, cf[2]);     Qk[10] = gat(r + C_, cf[3]);
        Qk[11] = gat(r + C_, cf[4]);
        Qk[12] = gat(r + 2*C_, cf[0]);   Qk[13] = gat(r + 2*C_, cf[1]);
        Qk[14] = gat(r + 2*C_, cf[2]);
        Qk[15] = gat(r + 3*C_, cf[0]);   Qk[16] = gat(r + 3*C_, cf[1]);
    };
    // bwd group applies rows r3 (high) down to r3-3; r3 points at the high row.
    auto loadqb = [&](float (&Qk)[NB], const float* r3) {
        const float* r2 = r3 - C_;
        const float* r1 = r3 - 2*C_;
        const float* r0 = r3 - 3*C_;
#pragma unroll
        for (int i = 0; i < 9; ++i) Qk[i]      = gat(r3, cb[i]);
#pragma unroll
        for (int i = 0; i < 7; ++i) Qk[9 + i]  = gat(r2, cb[i]);
#pragma unroll
        for (int i = 0; i < 5; ++i) Qk[16 + i] = gat(r1, cb[i]);
#pragma unroll
        for (int i = 0; i < 3; ++i) Qk[21 + i] = gat(r0, cb[i]);
        Qk[24] = r3[C_ - 1]; Qk[25] = r2[C_ - 1];
        Qk[26] = r1[C_ - 1]; Qk[27] = r0[C_ - 1];
    };

    // ---- composed 4-row forward update (verified in R3) ----
    auto fgroup4 = [&](float (&Qk)[NF]) {
        float A[9];
        A[0] = a;
#pragma unroll
        for (int i = 1; i <= 8; ++i) A[i] = __shfl_up(a, i) * msk[i];
        float B[7];
#pragma unroll
        for (int i = 0; i <= 6; ++i)
            B[i] = (A[i] + A[i + 1] + sg[i] * A[i + 2]) * (Qk[i] + EPSF);
        float Cc[5];
#pragma unroll
        for (int i = 0; i <= 4; ++i)
            Cc[i] = (B[i] + B[i + 1] + sg[i] * B[i + 2]) * (Qk[7 + i] + EPSF);
        float D[3];
#pragma unroll
        for (int i = 0; i <= 2; ++i)
            D[i] = (Cc[i] + Cc[i + 1] + sg[i] * Cc[i + 2]) * (Qk[12 + i] + EPSF);
        float z = a64;
        z = (z + A[0])  * (Qk[1]  + EPSF);
        z = (z + B[0])  * (Qk[8]  + EPSF);
        z = (z + Cc[0]) * (Qk[13] + EPSF);
        z = (z + D[0])  * (Qk[16] + EPSF);
        a64 = z;
        a = (D[0] + D[1] + sg[0] * D[2]) * (Qk[15] + EPSF);
    };

    // ---- composed 4-row backward update ----
    // beta_{t-1}[s] = q_t[s]*beta_t[s] + q_t[s+1]*beta_t[s+1] + skip(s+2)*q_t[s+2]*beta_t[s+2]
    auto bgroup4 = [&](float (&Qk)[NB]) {
        float BA[9];
        BA[0] = b;
#pragma unroll
        for (int i = 1; i <= 8; ++i) BA[i] = __shfl_down(b, i) * mdn[i];
        float G[9];
#pragma unroll
        for (int i = 0; i <= 8; ++i) G[i] = BA[i] * (Qk[i] + EPSF);
        float X[7];
#pragma unroll
        for (int i = 0; i <= 6; ++i) X[i] = G[i] + G[i + 1] + gd[i] * G[i + 2];
        float G2[7];
#pragma unroll
        for (int i = 0; i <= 6; ++i) G2[i] = X[i] * (Qk[9 + i] + EPSF);
        float X2[5];
#pragma unroll
        for (int i = 0; i <= 4; ++i) X2[i] = G2[i] + G2[i + 1] + gd[i] * G2[i + 2];
        float G3[5];
#pragma unroll
        for (int i = 0; i <= 4; ++i) G3[i] = X2[i] * (Qk[16 + i] + EPSF);
        float X3[3];
#pragma unroll
        for (int i = 0; i <= 2; ++i) X3[i] = G3[i] + G3[i + 1] + gd[i] * G3[i + 2];
        float G4[3];
#pragma unroll
        for (int i = 0; i <= 2; ++i) G4[i] = X3[i] * (Qk[21 + i] + EPSF);
        // beta[0] chain (valid on lane 0): beta'[0] = q[blank]*beta[0] + q[ext1]*beta[1]
        float z = b0;
        z = (Qk[24] + EPSF) * z + G[0];
        z = (Qk[25] + EPSF) * z + G2[0];
        z = (Qk[26] + EPSF) * z + G3[0];
        z = (Qk[27] + EPSF) * z + G4[0];
        b0 = z;
        b = G4[0] + G4[1] + gd[0] * G4[2];
    };

    // ---- exact pow2 rescale: 16 samples, stride 4 (lanes 3,7,...,63),
    // target 2^0. Guard m>=2^-40; step clamped to 2^±60.
    float smpF[16], smpB[16];
    auto sampleF = [&]() {
#pragma unroll
        for (int i = 0; i < 16; ++i) smpF[i] = __shfl(a, 4 * i + 3);
    };
    auto sampleB = [&]() {
#pragma unroll
        for (int i = 0; i < 16; ++i) smpB[i] = __shfl(b, 4 * i + 3);
    };
    auto apply = [&](const float* s, float& x, float& y, int& e) {
        float t[8];
#pragma unroll
        for (int i = 0; i < 8; ++i) t[i] = fmaxf(s[i], s[i + 8]);
#pragma unroll
        for (int i = 0; i < 4; ++i) t[i] = fmaxf(t[i], t[i + 4]);
        float m = fmaxf(fmaxf(t[0], t[1]), fmaxf(t[2], t[3]));
        m = fmaxf(m, 9.094947e-13f);                  // 2^-40 guard
        int be = (int)(__float_as_uint(m) >> 23);     // biased exponent
        be = (be < 67) ? 67 : ((be > 187) ? 187 : be);   // step in [2^-60, 2^60]
        e += be - 127;                                // target 2^0
        const float inv = __uint_as_float((unsigned)(254 - be) << 23);  // exact pow2
        x *= inv; y *= inv;
    };

#pragma unroll
    for (int k = 0; k < 3; ++k) {
        loadqf(Qf[k], bb + (size_t)(1 + 4 * k) * C_);
        loadqb(Qb[k], bb + (size_t)(511 - 4 * k) * C_);
    }
    sampleF(); sampleB();

    // 63 paired iterations; fwd group t, bwd group t. Branch-free clamped refills.
    for (int i0 = 0; i0 < 63; i0 += 3) {
#pragma unroll
        for (int k = 0; k < 3; ++k) {
            const int t = i0 + k;
            fgroup4(Qf[k]);
            bgroup4(Qb[k]);
            if ((t & 1) == 0) { apply(smpF, a, a64, ef); sampleF(); }
            else              { apply(smpB, b, b0, eb); sampleB(); }
            const int gf = (t + 3 <= 63) ? (t + 3) : 63;
            const int gb = (t + 3 <= 62) ? (t + 3) : 62;
            loadqf(Qf[k], bb + (size_t)(1 + 4 * gf) * C_);
            loadqb(Qb[k], bb + (size_t)(511 - 4 * gb) * C_);
        }
    }

    // Tail gathers for bwd single rows 259, 258, 257.
    float qs[12];
#pragma unroll
    for (int r = 0; r < 3; ++r) {
        const float* row = bb + (size_t)(259 - r) * C_;
        qs[4 * r + 0] = gat(row, cb[0]);
        qs[4 * r + 1] = gat(row, cb[1]);
        qs[4 * r + 2] = gat(row, cb[2]);
        qs[4 * r + 3] = row[C_ - 1];
    }

    fgroup4(Qf[0]);                 // fwd group 63 -> alpha_256
    apply(smpF, a, a64, ef);

    // bwd single steps: rows 259, 258, 257 -> beta_256
#pragma unroll
    for (int r = 0; r < 3; ++r) {
        const float g0  = b * (qs[4 * r + 0] + EPSF);
        const float ba1 = __shfl_down(b, 1) * mdn[1];
        const float ba2 = __shfl_down(b, 2) * mdn[2];
        const float g1  = ba1 * (qs[4 * r + 1] + EPSF);
        const float g2  = ba2 * (qs[4 * r + 2] + EPSF);
        b0 = (qs[4 * r + 3] + EPSF) * b0 + g0;
        b  = g0 + g1 + gd[0] * g2;
    }

    // ---- LOG-DOMAIN merge: loglik = logsumexp_s(log alpha[s] + log beta[s])
    //      + (ef+eb)*ln2.  Terms: s=0 on lane 0 (a*b0), s=lane+1 on lanes
    //      0..62 (shfl_down(a,1)*b), s=64 on lane 63 (a64*b).
    const float NEGB = -1e30f;
    auto lg = [&](float v) -> float { return (v > 0.f) ? __logf(v) : NEGB; };
    const float la   = lg(a);
    const float lb   = lg(b);
    const float ladn = __shfl_down(la, 1);   // log alpha[lane+1]
    float t1 = (lane <= 62) ? (ladn + lb) : NEGB;
    float t2 = NEGB;
    if (lane == 0)  t2 = la + lg(b0);
    if (lane == 63) t2 = lg(a64) + lb;

    float wmax = fmaxf(t1, t2);
#pragma unroll
    for (int off = 1; off < 64; off <<= 1) wmax = fmaxf(wmax, __shfl_xor(wmax, off));

    const float e1 = (t1 > -1e29f) ? __expf(t1 - wmax) : 0.f;
    const float e2 = (t2 > -1e29f) ? __expf(t2 - wmax) : 0.f;
    float p = e1 + e2;
#pragma unroll
    for (int off = 1; off < 64; off <<= 1) p += __shfl_xor(p, off);

    if (lane == 0) {
        const float ll = wmax + __logf(p) + (float)(ef + eb) * 0.6931471805599453f;
        out[bidx] = -ll;
    }
}

extern "C" void kernel_launch(void* const* d_in, const int* in_sizes, int n_in,
                              void* d_out, int out_size, void* d_ws, size_t ws_size,
                              hipStream_t stream) {
    const int*   y_true = (const int*)d_in[0];
    const float* y_pred = (const float*)d_in[1];
    float*       out    = (float*)d_out;

    const int B = out_size;   // output is [B,1]
    ctc_loss_kernel<<<B, 64, 0, stream>>>(y_true, y_pred, out);
}